// Round 1
// baseline (266.777 us; speedup 1.0000x reference)
//
#include <hip/hip_runtime.h>

#define N_NODES 50000
#define N_EDGES 800000
#define NCHUNK 64
#define NRANGE 4
#define RNODES (N_NODES / NRANGE)         // 12500
#define CEDGES (N_EDGES / NCHUNK)         // 12500
#define HIST_NB (NCHUNK * NRANGE)         // 256
#define SCAN_NB2 ((N_NODES + 63) / 64)    // 782 (64 nodes per scan block)

typedef __attribute__((ext_vector_type(8))) short short8;
typedef __attribute__((ext_vector_type(4))) float f32x4;

struct LPtrs { const float *W1, *W2, *W3, *Wl, *b1, *b3, *bl; };
struct AllPtrs { LPtrs l[3]; };

__device__ inline unsigned short f2b(float f) {
    union { float f; unsigned u; } c; c.f = f;
    return (unsigned short)((c.u + 0x7FFFu + ((c.u >> 16) & 1u)) >> 16);
}
__device__ inline float b2f(unsigned short h) {
    union { unsigned u; float f; } c; c.u = ((unsigned)h) << 16;
    return c.f;
}

// ---------------------------------------------------------------------------
// K1 (fused): blocks 0..255 build partial histograms with PACKED-u8 LDS
// atomics (4 counters per word; per-(chunk,node) count <= ~10 so no overflow);
// blocks 256..291 pack Wml = Wm@Wl into B-frag bf16 + bias rows.
__global__ __launch_bounds__(256) void histpack_kernel(const int* __restrict__ dst,
                                                       unsigned char* __restrict__ hist_part,
                                                       AllPtrs ap,
                                                       unsigned short* __restrict__ Wp,
                                                       float* __restrict__ rows) {
    __shared__ unsigned int h[5248];          // 21 KB; hist uses 3125 words
    const int t = threadIdx.x;
    if (blockIdx.x < HIST_NB) {
        const int chunk = blockIdx.x >> 2;
        const int range = blockIdx.x & 3;
        const int nbase = range * RNODES;
        for (int i = t; i < RNODES / 4; i += 256) h[i] = 0u;
        __syncthreads();
        const int* dp = dst + chunk * CEDGES;
        for (int i = t; i < CEDGES; i += 256) {
            int d = dp[i] - nbase;
            if ((unsigned)d < (unsigned)RNODES)
                atomicAdd(&h[d >> 2], 1u << ((d & 3) * 8));
        }
        __syncthreads();
        unsigned int* out = (unsigned int*)(hist_part + (long)chunk * N_NODES + nbase);
        for (int i = t; i < RNODES / 4; i += 256) out[i] = h[i];
    } else {
        float* sW = (float*)h;                // 64x65
        float* sL = (float*)h + 64 * 65;      // 64x17 (21 KB total)
        const int wi = blockIdx.x - HIST_NB;
        const int layer = wi / 12;
        const int ct = wi % 12;
        LPtrs L = ap.l[layer];
        const float* Wm = (ct < 4) ? L.W1 : (ct < 8) ? L.W2 : L.W3;
        const int colb = (ct & 3) * 16;
        for (int i = t; i < 64 * 64; i += 256) sW[(i >> 6) * 65 + (i & 63)] = Wm[i];
        for (int i = t; i < 64 * 16; i += 256) {
            int q = i >> 4, c = i & 15;
            sL[q * 17 + c] = L.Wl[q * 64 + colb + c];
        }
        __syncthreads();
        for (int local = t; local < 1024; local += 256) {
            int j = local & 7, lane = (local >> 3) & 63, s = local >> 9;
            int k = s * 32 + (lane >> 4) * 8 + j;
            int c = lane & 15;
            float acc = 0.f;
            #pragma unroll 8
            for (int q = 0; q < 64; ++q) acc += sW[k * 65 + q] * sL[q * 17 + c];
            Wp[layer * 12288 + ct * 1024 + local] = f2b(acc);
        }
        if (ct == 0 && t < 64) {
            int col = t;
            float r1 = 0.f, r3 = 0.f;
            for (int q = 0; q < 64; ++q) {
                float wl = L.Wl[q * 64 + col];
                r1 += L.b1[q] * wl;
                r3 += L.b3[q] * wl;
            }
            rows[layer * 128 + col] = r1;
            rows[layer * 128 + 64 + col] = r3 + L.bl[col];
        }
    }
}

// ---------------------------------------------------------------------------
// K2: per-node exclusive scan across 64 chunks, 4 THREADS PER NODE (16
// independent u8 loads each -> fully pipelined; was a 128-long dependent
// chain at 1 wave/SIMD). 64 nodes/block, 782 blocks (12 waves/CU).
// Wave 0 shuffle-scans the 64 node totals -> off (block-partial) + bsum.
__global__ __launch_bounds__(256) void scanA2_kernel(unsigned char* __restrict__ hist_part,
                                                     int* __restrict__ off,
                                                     int* __restrict__ deg,
                                                     int* __restrict__ bsum) {
    __shared__ int part[4][64];
    const int t = threadIdx.x;
    const int ln = t & 63;
    const int cg = t >> 6;                    // chunk group: 16 chunks each
    const int node = blockIdx.x * 64 + ln;
    unsigned char* col = hist_part + node;
    unsigned char v[16];
    int s = 0;
    if (node < N_NODES) {
        #pragma unroll
        for (int k = 0; k < 16; ++k) {
            v[k] = col[(long)(cg * 16 + k) * N_NODES];
            s += v[k];
        }
    }
    part[cg][ln] = s;
    __syncthreads();
    int run = 0, tot = 0;
    #pragma unroll
    for (int g = 0; g < 4; ++g) {
        int p = part[g][ln];
        if (g < cg) run += p;
        tot += p;
    }
    if (node < N_NODES) {
        #pragma unroll
        for (int k = 0; k < 16; ++k) {
            col[(long)(cg * 16 + k) * N_NODES] = (unsigned char)run;
            run += v[k];
        }
        if (cg == 0) deg[node] = tot;
    }
    if (cg == 0) {                            // wave 0: scan 64 node totals
        int x = tot;
        #pragma unroll
        for (int d = 1; d < 64; d <<= 1) {
            int u = __shfl_up(x, d, 64);
            if (ln >= d) x += u;
        }
        if (node < N_NODES) off[node] = x - tot;
        if (ln == 63) bsum[blockIdx.x] = x;
    }
}

// ---------------------------------------------------------------------------
// gemm core: a' = h@W1l; w = (h@W3l) - deg*((h@W2l) - row1) + row3.
__device__ __forceinline__ void gemm_body(int blk, int t,
    const unsigned short* __restrict__ hbf, const float* __restrict__ hf32,
    const unsigned short* __restrict__ Wp,
    const int* __restrict__ deg, const float* __restrict__ rows,
    unsigned short* __restrict__ abf, unsigned short* __restrict__ wbf, int n)
{
    const int lane = t & 63;
    const int quad = lane >> 4, lm = lane & 15;
    const int row_base = blk * 64 + (t >> 6) * 16;

    int arow = min(row_base + lm, n - 1);
    short8 a0, a1;
    if (hf32) {
        const float* hrow = hf32 + (long)arow * 64;
        #pragma unroll
        for (int j = 0; j < 8; ++j) {
            a0[j] = (short)f2b(hrow[quad * 8 + j]);
            a1[j] = (short)f2b(hrow[32 + quad * 8 + j]);
        }
    } else {
        const unsigned short* hrow = hbf + (long)arow * 64;
        a0 = *(const short8*)(hrow + quad * 8);
        a1 = *(const short8*)(hrow + 32 + quad * 8);
    }

    const short8* wp = (const short8*)Wp;
    f32x4 acc[12];
    #pragma unroll
    for (int ct = 0; ct < 12; ++ct) {
        f32x4 z = {0.f, 0.f, 0.f, 0.f};
        short8 w0 = wp[(ct * 2 + 0) * 64 + lane];
        short8 w1 = wp[(ct * 2 + 1) * 64 + lane];
        z = __builtin_amdgcn_mfma_f32_16x16x32_bf16(a0, w0, z, 0, 0, 0);
        z = __builtin_amdgcn_mfma_f32_16x16x32_bf16(a1, w1, z, 0, 0, 0);
        acc[ct] = z;
    }

    const int g0 = row_base + quad * 4;
    float dg[4];
    #pragma unroll
    for (int r = 0; r < 4; ++r) dg[r] = (float)deg[min(g0 + r, n - 1)];

    #pragma unroll
    for (int ct = 0; ct < 4; ++ct) {
        int col = ct * 16 + lm;
        float r1 = rows[col];
        float r3 = rows[64 + col];
        #pragma unroll
        for (int r = 0; r < 4; ++r) {
            int g = g0 + r;
            if (g < n) {
                abf[(long)g * 64 + col] = f2b(acc[ct][r]);
                float wv = acc[8 + ct][r] - dg[r] * (acc[4 + ct][r] - r1) + r3;
                wbf[(long)g * 64 + col] = f2b(wv);
            }
        }
    }
}

__global__ __launch_bounds__(256) void gemm3w_kernel(
    const unsigned short* __restrict__ hbf, const float* __restrict__ hf32,
    const unsigned short* __restrict__ Wp,
    const int* __restrict__ deg, const float* __restrict__ rows,
    unsigned short* __restrict__ abf, unsigned short* __restrict__ wbf, int n)
{
    gemm_body(blockIdx.x, threadIdx.x, hbf, hf32, Wp, deg, rows, abf, wbf, n);
}

// ---------------------------------------------------------------------------
// K3 (fused): blocks 0..255 fill csr (scanB over 782 block sums folded in,
// redundantly per block in LDS; block 0 publishes boff). Blocks 256..1037
// run the layer-0 GEMM concurrently (it only needs deg/Wp/rows, all ready) —
// overlaps the otherwise-serial fill.
__global__ __launch_bounds__(256) void fillgemm_kernel(
    const int* __restrict__ src, const int* __restrict__ dst,
    const int* __restrict__ off, const int* __restrict__ bsum,
    int* __restrict__ boff, const unsigned char* __restrict__ hist_part,
    int* __restrict__ csr,
    const float* __restrict__ x, const unsigned short* __restrict__ Wp,
    const int* __restrict__ deg, const float* __restrict__ rows,
    unsigned short* __restrict__ abf, unsigned short* __restrict__ wbf)
{
    __shared__ int cur[RNODES];               // 50 KB (scan reuses first 256)
    __shared__ int sb[SCAN_NB2 + 2];          // 3.1 KB scanned block sums
    if (blockIdx.x >= HIST_NB) {
        gemm_body(blockIdx.x - HIST_NB, threadIdx.x, nullptr, x, Wp, deg, rows,
                  abf, wbf, N_NODES);
        return;
    }
    const int t = threadIdx.x;

    // exclusive scan of bsum[782] in 4 rounds of 256 (cur[0..255] as scratch)
    int carry = 0;
    for (int base = 0; base < SCAN_NB2; base += 256) {
        int idx = base + t;
        int v = (idx < SCAN_NB2) ? bsum[idx] : 0;
        cur[t] = v;
        __syncthreads();
        #pragma unroll
        for (int d = 1; d < 256; d <<= 1) {
            int u = (t >= d) ? cur[t - d] : 0;
            __syncthreads();
            cur[t] += u;
            __syncthreads();
        }
        if (idx < SCAN_NB2) sb[idx] = carry + cur[t] - v;
        carry += cur[255];
        __syncthreads();
    }
    if (blockIdx.x == 0)
        for (int i = t; i < SCAN_NB2; i += 256) boff[i] = sb[i];

    const int chunk = blockIdx.x >> 2;
    const int range = blockIdx.x & 3;
    const int nbase = range * RNODES;
    const unsigned char* bp = hist_part + (long)chunk * N_NODES + nbase;
    const int* op = off + nbase;
    for (int i = t; i < RNODES; i += 256)
        cur[i] = op[i] + sb[(nbase + i) >> 6] + (int)bp[i];
    __syncthreads();
    const int* dp = dst + chunk * CEDGES;
    const int* sp = src + chunk * CEDGES;
    for (int i = t; i < CEDGES; i += 256) {
        int d = dp[i] - nbase;
        if ((unsigned)d < (unsigned)RNODES) {
            int pos = atomicAdd(&cur[d], 1);
            csr[pos] = sp[i];
        }
    }
}

// ---------------------------------------------------------------------------
// CSR gather + output: one wave per node; out = relu(S' + w).
__global__ __launch_bounds__(256) void gather_out_kernel(
    const int* __restrict__ off, const int* __restrict__ boff,
    const int* __restrict__ degv, const int* __restrict__ csr,
    const unsigned short* __restrict__ abf,
    const unsigned short* __restrict__ wbf,
    float* __restrict__ out_f, unsigned short* __restrict__ out_b, int last)
{
    int node = blockIdx.x * 4 + (threadIdx.x >> 6);
    int lane = threadIdx.x & 63;
    const int g = lane >> 4;
    const int f = (lane & 15) * 4;
    int beg = off[node] + boff[node >> 6];
    int end = beg + degv[node];
    float ax = 0.f, ay = 0.f, az = 0.f, aw = 0.f;
    int j = beg;
    for (; j + 16 <= end; j += 16) {
        int s0 = csr[j + g], s1 = csr[j + 4 + g];
        int s2 = csr[j + 8 + g], s3 = csr[j + 12 + g];
        ushort4 v0 = *(const ushort4*)(abf + (long)s0 * 64 + f);
        ushort4 v1 = *(const ushort4*)(abf + (long)s1 * 64 + f);
        ushort4 v2 = *(const ushort4*)(abf + (long)s2 * 64 + f);
        ushort4 v3 = *(const ushort4*)(abf + (long)s3 * 64 + f);
        ax += b2f(v0.x) + b2f(v1.x) + b2f(v2.x) + b2f(v3.x);
        ay += b2f(v0.y) + b2f(v1.y) + b2f(v2.y) + b2f(v3.y);
        az += b2f(v0.z) + b2f(v1.z) + b2f(v2.z) + b2f(v3.z);
        aw += b2f(v0.w) + b2f(v1.w) + b2f(v2.w) + b2f(v3.w);
    }
    for (; j + 8 <= end; j += 8) {
        int s0 = csr[j + g], s1 = csr[j + 4 + g];
        ushort4 v0 = *(const ushort4*)(abf + (long)s0 * 64 + f);
        ushort4 v1 = *(const ushort4*)(abf + (long)s1 * 64 + f);
        ax += b2f(v0.x) + b2f(v1.x);
        ay += b2f(v0.y) + b2f(v1.y);
        az += b2f(v0.z) + b2f(v1.z);
        aw += b2f(v0.w) + b2f(v1.w);
    }
    for (; j < end; j += 4) {
        int jj = j + g;
        if (jj < end) {
            int s0 = csr[jj];
            ushort4 v0 = *(const ushort4*)(abf + (long)s0 * 64 + f);
            ax += b2f(v0.x); ay += b2f(v0.y); az += b2f(v0.z); aw += b2f(v0.w);
        }
    }
    #pragma unroll
    for (int m = 16; m < 64; m <<= 1) {
        ax += __shfl_xor(ax, m, 64);
        ay += __shfl_xor(ay, m, 64);
        az += __shfl_xor(az, m, 64);
        aw += __shfl_xor(aw, m, 64);
    }
    if (g == 0) {
        ushort4 wv = *(const ushort4*)(wbf + (long)node * 64 + f);
        float o0 = fmaxf(ax + b2f(wv.x), 0.f);
        float o1 = fmaxf(ay + b2f(wv.y), 0.f);
        float o2 = fmaxf(az + b2f(wv.z), 0.f);
        float o3 = fmaxf(aw + b2f(wv.w), 0.f);
        if (last) {
            float4 o = {o0, o1, o2, o3};
            *(float4*)(out_f + (long)node * 64 + f) = o;
        } else {
            ushort4 o;
            o.x = f2b(o0); o.y = f2b(o1); o.z = f2b(o2); o.w = f2b(o3);
            *(ushort4*)(out_b + (long)node * 64 + f) = o;
        }
    }
}

// ---------------------------------------------------------------------------
extern "C" void kernel_launch(void* const* d_in, const int* in_sizes, int n_in,
                              void* d_out, int out_size, void* d_ws, size_t ws_size,
                              hipStream_t stream) {
    const float* x  = (const float*)d_in[0];
    const int*   ei = (const int*)d_in[1];
    const int*   src = ei;
    const int*   dst = ei + N_EDGES;

    char* wsb = (char*)d_ws;
    unsigned char*  hist_part = (unsigned char*)(wsb);          // 3.2 MB (u8)
    unsigned short* abf  = (unsigned short*)(wsb + 12800000);   // 6.4 MB
    unsigned short* wbf  = (unsigned short*)(wsb + 19200000);   // 6.4 MB
    unsigned short* h1   = (unsigned short*)(wsb + 25600000);   // 6.4 MB
    unsigned short* Wp   = (unsigned short*)(wsb + 38400000);   // 72 KB
    float*          rows = (float*)(wsb + 38500000);            // 1.5 KB
    int* off  = (int*)(wsb + 38600000);                         // N_NODES
    int* deg  = off + N_NODES;                                  // N_NODES
    int* bsum = deg + N_NODES;                                  // SCAN_NB2
    int* boff = bsum + 1024;                                    // SCAN_NB2
    int* csr  = boff + 1024;                                    // N_EDGES

    const int NBLK = (N_NODES + 63) / 64;    // 782

    AllPtrs ap;
    for (int l = 0; l < 3; ++l) {
        int base = 2 + l * 7;
        ap.l[l].W1 = (const float*)d_in[base + 0];
        ap.l[l].b1 = (const float*)d_in[base + 1];
        ap.l[l].W2 = (const float*)d_in[base + 2];
        ap.l[l].W3 = (const float*)d_in[base + 3];
        ap.l[l].b3 = (const float*)d_in[base + 4];
        ap.l[l].Wl = (const float*)d_in[base + 5];
        ap.l[l].bl = (const float*)d_in[base + 6];
    }

    // ---- CSR build + weight pack + layer-0 GEMM: 3 launches ----
    histpack_kernel<<<HIST_NB + 36, 256, 0, stream>>>(dst, hist_part, ap, Wp, rows);
    scanA2_kernel<<<SCAN_NB2, 256, 0, stream>>>(hist_part, off, deg, bsum);
    fillgemm_kernel<<<HIST_NB + NBLK, 256, 0, stream>>>(
        src, dst, off, bsum, boff, hist_part, csr,
        x, Wp, deg, rows, abf, wbf);

    // layer 0 gather (gemm0 already done inside fillgemm)
    gather_out_kernel<<<N_NODES / 4, 256, 0, stream>>>(
        off, boff, deg, csr, abf, wbf, (float*)d_out, h1, 0);

    const unsigned short* hin = h1;
    for (int l = 1; l < 3; ++l) {
        gemm3w_kernel<<<NBLK, 256, 0, stream>>>(
            hin, nullptr, Wp + l * 12288, deg, rows + l * 128,
            abf, wbf, N_NODES);
        gather_out_kernel<<<N_NODES / 4, 256, 0, stream>>>(
            off, boff, deg, csr, abf, wbf, (float*)d_out, h1, (l == 2));
        hin = h1;
    }
}

// Round 2
// 262.748 us; speedup vs baseline: 1.0153x; 1.0153x over previous
//
#include <hip/hip_runtime.h>

#define N_NODES 50000
#define N_PAD 50048                       // 782*64, node-space padded for alignment
#define N_EDGES 800000
#define NCHUNK 64
#define NRANGE 8
#define RN 6256                           // N_PAD / NRANGE, divisible by 16
#define CEDGES (N_EDGES / NCHUNK)         // 12500
#define HIST_NB (NCHUNK * NRANGE)         // 512
#define SCAN_NB2 (N_PAD / 64)             // 782 (64 nodes per scan block)

typedef __attribute__((ext_vector_type(8))) short short8;
typedef __attribute__((ext_vector_type(4))) float f32x4;

struct LPtrs { const float *W1, *W2, *W3, *Wl, *b1, *b3, *bl; };
struct AllPtrs { LPtrs l[3]; };

__device__ inline unsigned short f2b(float f) {
    union { float f; unsigned u; } c; c.f = f;
    return (unsigned short)((c.u + 0x7FFFu + ((c.u >> 16) & 1u)) >> 16);
}
__device__ inline float b2f(unsigned short h) {
    union { unsigned u; float f; } c; c.u = ((unsigned)h) << 16;
    return c.f;
}

// ---------------------------------------------------------------------------
// K1 (fused): blocks 0..511 build partial histograms with PACKED-u8 LDS
// atomics (4 counters/word; per-(chunk,node) count <= ~10, no overflow);
// blocks 512..547 pack Wml = Wm@Wl into B-frag bf16 + bias rows.
__global__ __launch_bounds__(256) void histpack_kernel(const int* __restrict__ dst,
                                                       unsigned char* __restrict__ hist_part,
                                                       AllPtrs ap,
                                                       unsigned short* __restrict__ Wp,
                                                       float* __restrict__ rows) {
    __shared__ unsigned int h[5248];          // 21 KB; hist path uses 1564 words
    const int t = threadIdx.x;
    if (blockIdx.x < HIST_NB) {
        const int chunk = blockIdx.x >> 3;
        const int range = blockIdx.x & 7;
        const int nbase = range * RN;
        for (int i = t; i < RN / 4; i += 256) h[i] = 0u;
        __syncthreads();
        const int* dp = dst + chunk * CEDGES;
        for (int i = t; i < CEDGES; i += 256) {
            int d = dp[i] - nbase;
            if ((unsigned)d < (unsigned)RN)
                atomicAdd(&h[d >> 2], 1u << ((d & 3) * 8));
        }
        __syncthreads();
        unsigned int* out = (unsigned int*)(hist_part + (long)chunk * N_PAD + nbase);
        for (int i = t; i < RN / 4; i += 256) out[i] = h[i];
    } else {
        float* sW = (float*)h;                // 64x65
        float* sL = (float*)h + 64 * 65;      // 64x17 (21 KB total)
        const int wi = blockIdx.x - HIST_NB;
        const int layer = wi / 12;
        const int ct = wi % 12;
        LPtrs L = ap.l[layer];
        const float* Wm = (ct < 4) ? L.W1 : (ct < 8) ? L.W2 : L.W3;
        const int colb = (ct & 3) * 16;
        for (int i = t; i < 64 * 64; i += 256) sW[(i >> 6) * 65 + (i & 63)] = Wm[i];
        for (int i = t; i < 64 * 16; i += 256) {
            int q = i >> 4, c = i & 15;
            sL[q * 17 + c] = L.Wl[q * 64 + colb + c];
        }
        __syncthreads();
        for (int local = t; local < 1024; local += 256) {
            int j = local & 7, lane = (local >> 3) & 63, s = local >> 9;
            int k = s * 32 + (lane >> 4) * 8 + j;
            int c = lane & 15;
            float acc = 0.f;
            #pragma unroll 8
            for (int q = 0; q < 64; ++q) acc += sW[k * 65 + q] * sL[q * 17 + c];
            Wp[layer * 12288 + ct * 1024 + local] = f2b(acc);
        }
        if (ct == 0 && t < 64) {
            int col = t;
            float r1 = 0.f, r3 = 0.f;
            for (int q = 0; q < 64; ++q) {
                float wl = L.Wl[q * 64 + col];
                r1 += L.b1[q] * wl;
                r3 += L.b3[q] * wl;
            }
            rows[layer * 128 + col] = r1;
            rows[layer * 128 + 64 + col] = r3 + L.bl[col];
        }
    }
}

// ---------------------------------------------------------------------------
// K2: per-node exclusive scan across 64 chunks, 4 threads per node (16
// independent u8 loads each). 64 nodes/block, 782 blocks (12 waves/CU).
// Wave 0 shuffle-scans the 64 node totals -> off (block-partial) + bsum.
__global__ __launch_bounds__(256) void scanA2_kernel(unsigned char* __restrict__ hist_part,
                                                     int* __restrict__ off,
                                                     int* __restrict__ deg,
                                                     int* __restrict__ bsum) {
    __shared__ int part[4][64];
    const int t = threadIdx.x;
    const int ln = t & 63;
    const int cg = t >> 6;                    // chunk group: 16 chunks each
    const int node = blockIdx.x * 64 + ln;    // < N_PAD always
    unsigned char* col = hist_part + node;
    unsigned char v[16];
    int s = 0;
    #pragma unroll
    for (int k = 0; k < 16; ++k) {
        v[k] = col[(long)(cg * 16 + k) * N_PAD];
        s += v[k];
    }
    part[cg][ln] = s;
    __syncthreads();
    int run = 0, tot = 0;
    #pragma unroll
    for (int g = 0; g < 4; ++g) {
        int p = part[g][ln];
        if (g < cg) run += p;
        tot += p;
    }
    #pragma unroll
    for (int k = 0; k < 16; ++k) {
        col[(long)(cg * 16 + k) * N_PAD] = (unsigned char)run;
        run += v[k];
    }
    if (cg == 0 && node < N_NODES) deg[node] = tot;
    if (cg == 0) {                            // wave 0: scan 64 node totals
        int x = tot;
        #pragma unroll
        for (int d = 1; d < 64; d <<= 1) {
            int u = __shfl_up(x, d, 64);
            if (ln >= d) x += u;
        }
        if (node < N_NODES) off[node] = x - tot;
        if (ln == 63) bsum[blockIdx.x] = x;
    }
}

// ---------------------------------------------------------------------------
// gemm core: a' = h@W1l; w = (h@W3l) - deg*((h@W2l) - row1) + row3.
__device__ __forceinline__ void gemm_body(int blk, int t,
    const unsigned short* __restrict__ hbf, const float* __restrict__ hf32,
    const unsigned short* __restrict__ Wp,
    const int* __restrict__ deg, const float* __restrict__ rows,
    unsigned short* __restrict__ abf, unsigned short* __restrict__ wbf, int n)
{
    const int lane = t & 63;
    const int quad = lane >> 4, lm = lane & 15;
    const int row_base = blk * 64 + (t >> 6) * 16;

    int arow = min(row_base + lm, n - 1);
    short8 a0, a1;
    if (hf32) {
        const float* hrow = hf32 + (long)arow * 64;
        #pragma unroll
        for (int j = 0; j < 8; ++j) {
            a0[j] = (short)f2b(hrow[quad * 8 + j]);
            a1[j] = (short)f2b(hrow[32 + quad * 8 + j]);
        }
    } else {
        const unsigned short* hrow = hbf + (long)arow * 64;
        a0 = *(const short8*)(hrow + quad * 8);
        a1 = *(const short8*)(hrow + 32 + quad * 8);
    }

    const short8* wp = (const short8*)Wp;
    f32x4 acc[12];
    #pragma unroll
    for (int ct = 0; ct < 12; ++ct) {
        f32x4 z = {0.f, 0.f, 0.f, 0.f};
        short8 w0 = wp[(ct * 2 + 0) * 64 + lane];
        short8 w1 = wp[(ct * 2 + 1) * 64 + lane];
        z = __builtin_amdgcn_mfma_f32_16x16x32_bf16(a0, w0, z, 0, 0, 0);
        z = __builtin_amdgcn_mfma_f32_16x16x32_bf16(a1, w1, z, 0, 0, 0);
        acc[ct] = z;
    }

    const int g0 = row_base + quad * 4;
    float dg[4];
    #pragma unroll
    for (int r = 0; r < 4; ++r) dg[r] = (float)deg[min(g0 + r, n - 1)];

    #pragma unroll
    for (int ct = 0; ct < 4; ++ct) {
        int col = ct * 16 + lm;
        float r1 = rows[col];
        float r3 = rows[64 + col];
        #pragma unroll
        for (int r = 0; r < 4; ++r) {
            int g = g0 + r;
            if (g < n) {
                abf[(long)g * 64 + col] = f2b(acc[ct][r]);
                float wv = acc[8 + ct][r] - dg[r] * (acc[4 + ct][r] - r1) + r3;
                wbf[(long)g * 64 + col] = f2b(wv);
            }
        }
    }
}

__global__ __launch_bounds__(256) void gemm3w_kernel(
    const unsigned short* __restrict__ hbf, const float* __restrict__ hf32,
    const unsigned short* __restrict__ Wp,
    const int* __restrict__ deg, const float* __restrict__ rows,
    unsigned short* __restrict__ abf, unsigned short* __restrict__ wbf, int n)
{
    gemm_body(blockIdx.x, threadIdx.x, hbf, hf32, Wp, deg, rows, abf, wbf, n);
}

// ---------------------------------------------------------------------------
// K3 (fused): blocks 0..511 fill csr (single-round scan of 782 block sums,
// 4 contiguous/thread; block 0 publishes boff). Blocks 512..1293 run the
// layer-0 GEMM concurrently (needs only deg/Wp/rows, all ready).
__global__ __launch_bounds__(256) void fillgemm_kernel(
    const int* __restrict__ src, const int* __restrict__ dst,
    const int* __restrict__ off, const int* __restrict__ bsum,
    int* __restrict__ boff, const unsigned char* __restrict__ hist_part,
    int* __restrict__ csr,
    const float* __restrict__ x, const unsigned short* __restrict__ Wp,
    const int* __restrict__ deg, const float* __restrict__ rows,
    unsigned short* __restrict__ abf, unsigned short* __restrict__ wbf)
{
    __shared__ int cur[RN];                   // 25 KB (scan reuses first 256)
    __shared__ int sb[1024];                  // 4 KB scanned block sums
    if (blockIdx.x >= HIST_NB) {
        gemm_body(blockIdx.x - HIST_NB, threadIdx.x, nullptr, x, Wp, deg, rows,
                  abf, wbf, N_NODES);
        return;
    }
    const int t = threadIdx.x;

    // exclusive scan of bsum[782]: 4 contiguous values/thread + one 256-scan
    const int i0 = t * 4;
    int a0 = (i0 + 0 < SCAN_NB2) ? bsum[i0 + 0] : 0;
    int a1 = (i0 + 1 < SCAN_NB2) ? bsum[i0 + 1] : 0;
    int a2 = (i0 + 2 < SCAN_NB2) ? bsum[i0 + 2] : 0;
    int a3 = (i0 + 3 < SCAN_NB2) ? bsum[i0 + 3] : 0;
    int s = a0 + a1 + a2 + a3;
    cur[t] = s;
    __syncthreads();
    #pragma unroll
    for (int d = 1; d < 256; d <<= 1) {
        int u = (t >= d) ? cur[t - d] : 0;
        __syncthreads();
        cur[t] += u;
        __syncthreads();
    }
    int excl = cur[t] - s;
    sb[i0 + 0] = excl;
    sb[i0 + 1] = excl + a0;
    sb[i0 + 2] = excl + a0 + a1;
    sb[i0 + 3] = excl + a0 + a1 + a2;
    __syncthreads();
    if (blockIdx.x == 0)
        for (int i = t; i < SCAN_NB2; i += 256) boff[i] = sb[i];

    const int chunk = blockIdx.x >> 3;
    const int range = blockIdx.x & 7;
    const int nbase = range * RN;
    const unsigned char* bp = hist_part + (long)chunk * N_PAD + nbase;
    const int* op = off + nbase;
    const int lim = min(RN, N_NODES - nbase);
    for (int i = t; i < lim; i += 256)
        cur[i] = op[i] + sb[(nbase + i) >> 6] + (int)bp[i];
    __syncthreads();
    const int* dp = dst + chunk * CEDGES;
    const int* sp = src + chunk * CEDGES;
    for (int i = t; i < CEDGES; i += 256) {
        int d = dp[i] - nbase;
        if ((unsigned)d < (unsigned)RN) {
            int pos = atomicAdd(&cur[d], 1);
            csr[pos] = sp[i];
        }
    }
}

// ---------------------------------------------------------------------------
// CSR gather + output: one wave per node; out = relu(S' + w).
__global__ __launch_bounds__(256) void gather_out_kernel(
    const int* __restrict__ off, const int* __restrict__ boff,
    const int* __restrict__ degv, const int* __restrict__ csr,
    const unsigned short* __restrict__ abf,
    const unsigned short* __restrict__ wbf,
    float* __restrict__ out_f, unsigned short* __restrict__ out_b, int last)
{
    int node = blockIdx.x * 4 + (threadIdx.x >> 6);
    int lane = threadIdx.x & 63;
    const int g = lane >> 4;
    const int f = (lane & 15) * 4;
    int beg = off[node] + boff[node >> 6];
    int end = beg + degv[node];
    float ax = 0.f, ay = 0.f, az = 0.f, aw = 0.f;
    int j = beg;
    for (; j + 16 <= end; j += 16) {
        int s0 = csr[j + g], s1 = csr[j + 4 + g];
        int s2 = csr[j + 8 + g], s3 = csr[j + 12 + g];
        ushort4 v0 = *(const ushort4*)(abf + (long)s0 * 64 + f);
        ushort4 v1 = *(const ushort4*)(abf + (long)s1 * 64 + f);
        ushort4 v2 = *(const ushort4*)(abf + (long)s2 * 64 + f);
        ushort4 v3 = *(const ushort4*)(abf + (long)s3 * 64 + f);
        ax += b2f(v0.x) + b2f(v1.x) + b2f(v2.x) + b2f(v3.x);
        ay += b2f(v0.y) + b2f(v1.y) + b2f(v2.y) + b2f(v3.y);
        az += b2f(v0.z) + b2f(v1.z) + b2f(v2.z) + b2f(v3.z);
        aw += b2f(v0.w) + b2f(v1.w) + b2f(v2.w) + b2f(v3.w);
    }
    for (; j + 8 <= end; j += 8) {
        int s0 = csr[j + g], s1 = csr[j + 4 + g];
        ushort4 v0 = *(const ushort4*)(abf + (long)s0 * 64 + f);
        ushort4 v1 = *(const ushort4*)(abf + (long)s1 * 64 + f);
        ax += b2f(v0.x) + b2f(v1.x);
        ay += b2f(v0.y) + b2f(v1.y);
        az += b2f(v0.z) + b2f(v1.z);
        aw += b2f(v0.w) + b2f(v1.w);
    }
    for (; j < end; j += 4) {
        int jj = j + g;
        if (jj < end) {
            int s0 = csr[jj];
            ushort4 v0 = *(const ushort4*)(abf + (long)s0 * 64 + f);
            ax += b2f(v0.x); ay += b2f(v0.y); az += b2f(v0.z); aw += b2f(v0.w);
        }
    }
    #pragma unroll
    for (int m = 16; m < 64; m <<= 1) {
        ax += __shfl_xor(ax, m, 64);
        ay += __shfl_xor(ay, m, 64);
        az += __shfl_xor(az, m, 64);
        aw += __shfl_xor(aw, m, 64);
    }
    if (g == 0) {
        ushort4 wv = *(const ushort4*)(wbf + (long)node * 64 + f);
        float o0 = fmaxf(ax + b2f(wv.x), 0.f);
        float o1 = fmaxf(ay + b2f(wv.y), 0.f);
        float o2 = fmaxf(az + b2f(wv.z), 0.f);
        float o3 = fmaxf(aw + b2f(wv.w), 0.f);
        if (last) {
            float4 o = {o0, o1, o2, o3};
            *(float4*)(out_f + (long)node * 64 + f) = o;
        } else {
            ushort4 o;
            o.x = f2b(o0); o.y = f2b(o1); o.z = f2b(o2); o.w = f2b(o3);
            *(ushort4*)(out_b + (long)node * 64 + f) = o;
        }
    }
}

// ---------------------------------------------------------------------------
extern "C" void kernel_launch(void* const* d_in, const int* in_sizes, int n_in,
                              void* d_out, int out_size, void* d_ws, size_t ws_size,
                              hipStream_t stream) {
    const float* x  = (const float*)d_in[0];
    const int*   ei = (const int*)d_in[1];
    const int*   src = ei;
    const int*   dst = ei + N_EDGES;

    char* wsb = (char*)d_ws;
    unsigned char*  hist_part = (unsigned char*)(wsb);          // 3.2 MB (u8, N_PAD stride)
    unsigned short* abf  = (unsigned short*)(wsb + 12800000);   // 6.4 MB
    unsigned short* wbf  = (unsigned short*)(wsb + 19200000);   // 6.4 MB
    unsigned short* h1   = (unsigned short*)(wsb + 25600000);   // 6.4 MB
    unsigned short* Wp   = (unsigned short*)(wsb + 38400000);   // 72 KB
    float*          rows = (float*)(wsb + 38500000);            // 1.5 KB
    int* off  = (int*)(wsb + 38600000);                         // N_NODES
    int* deg  = off + N_NODES;                                  // N_NODES
    int* bsum = deg + N_NODES;                                  // SCAN_NB2 (pad 1024)
    int* boff = bsum + 1024;                                    // SCAN_NB2 (pad 1024)
    int* csr  = boff + 1024;                                    // N_EDGES

    const int NBLK = (N_NODES + 63) / 64;    // 782

    AllPtrs ap;
    for (int l = 0; l < 3; ++l) {
        int base = 2 + l * 7;
        ap.l[l].W1 = (const float*)d_in[base + 0];
        ap.l[l].b1 = (const float*)d_in[base + 1];
        ap.l[l].W2 = (const float*)d_in[base + 2];
        ap.l[l].W3 = (const float*)d_in[base + 3];
        ap.l[l].b3 = (const float*)d_in[base + 4];
        ap.l[l].Wl = (const float*)d_in[base + 5];
        ap.l[l].bl = (const float*)d_in[base + 6];
    }

    // ---- CSR build + weight pack + layer-0 GEMM: 3 launches ----
    histpack_kernel<<<HIST_NB + 36, 256, 0, stream>>>(dst, hist_part, ap, Wp, rows);
    scanA2_kernel<<<SCAN_NB2, 256, 0, stream>>>(hist_part, off, deg, bsum);
    fillgemm_kernel<<<HIST_NB + NBLK, 256, 0, stream>>>(
        src, dst, off, bsum, boff, hist_part, csr,
        x, Wp, deg, rows, abf, wbf);

    // layer 0 gather (gemm0 already done inside fillgemm)
    gather_out_kernel<<<N_NODES / 4, 256, 0, stream>>>(
        off, boff, deg, csr, abf, wbf, (float*)d_out, h1, 0);

    const unsigned short* hin = h1;
    for (int l = 1; l < 3; ++l) {
        gemm3w_kernel<<<NBLK, 256, 0, stream>>>(
            hin, nullptr, Wp + l * 12288, deg, rows + l * 128,
            abf, wbf, N_NODES);
        gather_out_kernel<<<N_NODES / 4, 256, 0, stream>>>(
            off, boff, deg, csr, abf, wbf, (float*)d_out, h1, (l == 2));
        hin = h1;
    }
}